// Round 3
// baseline (60.736 us; speedup 1.0000x reference)
//
#include <hip/hip_runtime.h>
#include <math.h>

#define M_SAMPLES 131072
#define NBLK 512
#define BLK 256

constexpr int ui(int i, int j) { return i * 8 - i * (i + 1) / 2 + j; }

__device__ __forceinline__ float logaddexp_f(float a, float b) {
    float m = fmaxf(a, b);
    float d = fminf(a, b) - m;
    return m + __logf(1.f + __expf(d));
}

#define CMULR(ar, ai, br, bi) ((ar) * (br) - (ai) * (bi))
#define CMULI(ar, ai, br, bi) ((ar) * (bi) + (ai) * (br))

__global__ __launch_bounds__(BLK, 2) void bez_main_kernel(
    const float* __restrict__ P0, const float* __restrict__ Pd,
    const float* __restrict__ Pmid, const float* __restrict__ ts,
    float* __restrict__ partial, int* __restrict__ counter,
    float* __restrict__ out)
{
    __shared__ float sP[8][8][2];
    __shared__ float sQ[7][8][2];
    __shared__ float sR[6][8][2];
    __shared__ float red[4][3];
    __shared__ int lastflag;

    const int tid = threadIdx.x;
    if (tid < 16) { sP[0][tid >> 1][tid & 1] = P0[tid]; sP[7][tid >> 1][tid & 1] = Pd[tid]; }
    if (tid < 96) { int r = tid / 16, rem = tid % 16; sP[1 + r][rem >> 1][rem & 1] = Pmid[tid]; }
    __syncthreads();
    if (tid < 112) {
        int k = tid / 16, rem = tid % 16, j = rem >> 1, c = rem & 1;
        sQ[k][j][c] = 7.f * (sP[k + 1][j][c] - sP[k][j][c]);
    }
    __syncthreads();
    if (tid < 96) {
        int k = tid / 16, rem = tid % 16, j = rem >> 1, c = rem & 1;
        sR[k][j][c] = 6.f * (sQ[k + 1][j][c] - sQ[k][j][c]);
    }
    __syncthreads();

    const int gid = blockIdx.x * BLK + tid;
    const float t = ts[gid];
    const float u = 1.f - t;
    float tp[8], up[8];
    tp[0] = 1.f; up[0] = 1.f;
#pragma unroll
    for (int k = 1; k < 8; ++k) { tp[k] = tp[k - 1] * t; up[k] = up[k - 1] * u; }

    const float C7[8] = {1.f, 7.f, 21.f, 35.f, 35.f, 21.f, 7.f, 1.f};
    const float C6[7] = {1.f, 6.f, 15.f, 20.f, 15.f, 6.f, 1.f};
    const float C5[6] = {1.f, 5.f, 10.f, 10.f, 5.f, 1.f};
    float b7[8], b6[7], b5[6];
#pragma unroll
    for (int k = 0; k < 8; ++k) b7[k] = C7[k] * tp[k] * up[7 - k];
#pragma unroll
    for (int k = 0; k < 7; ++k) b6[k] = C6[k] * tp[k] * up[6 - k];
#pragma unroll
    for (int k = 0; k < 6; ++k) b5[k] = C5[k] * tp[k] * up[5 - k];

    // T: monic-poly coefficient samples (8 complex), plus speed^2 / accel^2
    float Tr[8], Ti[8];
#pragma unroll
    for (int j = 0; j < 8; ++j) {
        float ar = 0.f, ai = 0.f;
#pragma unroll
        for (int k = 0; k < 8; ++k) { ar += b7[k] * sP[k][j][0]; ai += b7[k] * sP[k][j][1]; }
        Tr[j] = ar; Ti[j] = ai;
    }
    float sp2 = 0.f;
#pragma unroll
    for (int j = 0; j < 8; ++j) {
        float ar = 0.f, ai = 0.f;
#pragma unroll
        for (int k = 0; k < 7; ++k) { ar += b6[k] * sQ[k][j][0]; ai += b6[k] * sQ[k][j][1]; }
        sp2 += ar * ar + ai * ai;
    }
    float ac2 = 0.f;
#pragma unroll
    for (int j = 0; j < 8; ++j) {
        float ar = 0.f, ai = 0.f;
#pragma unroll
        for (int k = 0; k < 6; ++k) { ar += b5[k] * sR[k][j][0]; ai += b5[k] * sR[k][j][1]; }
        ac2 += ar * ar + ai * ai;
    }
    const float speed = sqrtf(sp2);

    // Ascending coefficients: f_j = T_{7-j} (j=0..7), f_8 = 1 (monic).
    // g_j = f'_j = (j+1) f_{j+1}; c_{a,b} = f_a g_b - f_b g_a
    //            = (b+1) f_a*f_{b+1} - (a+1) f_b*f_{a+1}   (a,b <= 7)
    // c_{8,b} = g_b = (b+1) f_{b+1}.
    float fr[9], fi[9];
#pragma unroll
    for (int j = 0; j < 8; ++j) { fr[j] = Tr[7 - j]; fi[j] = Ti[7 - j]; }
    fr[8] = 1.f; fi[8] = 0.f;

    // Upper triangle of the complex-symmetric Bezout matrix:
    // B[i][j] = sum_m c_{i+1+m, j-m}  (all terms share anti-diag s = i+j+1)
    // built per anti-diagonal with a running suffix sum; c computed on the fly.
    float UR[36], UI[36];
#pragma unroll
    for (int s = 1; s <= 15; ++s) {
        const int i_max = (s - 1) / 2;
        const int i_min = (s <= 8) ? 0 : (s - 8);
        const int a_hi = (s < 8) ? s : 8;
        float runr = 0.f, runi = 0.f;
#pragma unroll
        for (int a = i_max + 1; a <= a_hi; ++a) {
            const int b = s - a;
            if (a == b) continue;                 // c_{a,a} = 0
            if (a == 8) {                         // c_{8,b} = g_b
                runr += (float)(b + 1) * fr[b + 1];
                runi += (float)(b + 1) * fi[b + 1];
            } else {
                float xr = CMULR(fr[a], fi[a], fr[b + 1], fi[b + 1]);
                float xi = CMULI(fr[a], fi[a], fr[b + 1], fi[b + 1]);
                float yr = CMULR(fr[b], fi[b], fr[a + 1], fi[a + 1]);
                float yi = CMULI(fr[b], fi[b], fr[a + 1], fi[a + 1]);
                runr += (float)(b + 1) * xr - (float)(a + 1) * yr;
                runi += (float)(b + 1) * xi - (float)(a + 1) * yi;
            }
        }
        UR[ui(i_max, s - 1 - i_max)] = runr; UI[ui(i_max, s - 1 - i_max)] = runi;
#pragma unroll
        for (int i = i_max; i > i_min; --i) {
            const int a = i, b = s - i;           // a < b <= 7 here
            float xr = CMULR(fr[a], fi[a], fr[b + 1], fi[b + 1]);
            float xi = CMULI(fr[a], fi[a], fr[b + 1], fi[b + 1]);
            float yr = CMULR(fr[b], fi[b], fr[a + 1], fi[a + 1]);
            float yi = CMULI(fr[b], fi[b], fr[a + 1], fi[a + 1]);
            runr += (float)(b + 1) * xr - (float)(a + 1) * yr;
            runi += (float)(b + 1) * xi - (float)(a + 1) * yi;
            UR[ui(i - 1, s - i)] = runr; UI[ui(i - 1, s - i)] = runi;
        }
    }

    // Pivot-free complex-symmetric LDL^T on the upper triangle.
    // log|det| accumulated via mantissa-product + exponent-sum (frexp trick):
    // avoids 8 serial __logf and is inherently Inf/NaN-bounding.
    float logm = 1.f; int loge = 0;
#pragma unroll
    for (int k = 0; k < 8; ++k) {
        float dr = UR[ui(k, k)], di = UI[ui(k, k)];
        float pm2 = dr * dr + di * di;
        unsigned ub = __float_as_uint(pm2);
        loge += (int)(ub >> 23) - 126;
        logm *= __uint_as_float((ub & 0x007fffffu) | 0x3f000000u);  // [0.5, 1)
        if (k < 7) {
            float is = __builtin_amdgcn_rcpf(pm2);
            is = (pm2 > 1e-30f) ? is : 0.f;
            float ivr = dr * is, ivi = -di * is;          // 1/d
            float wr[8], wi[8];
#pragma unroll
            for (int i = k + 1; i < 8; ++i) {
                float ar = UR[ui(k, i)], ai = UI[ui(k, i)];   // A[i][k] by symmetry
                wr[i] = ar * ivr - ai * ivi;
                wi[i] = ar * ivi + ai * ivr;
            }
#pragma unroll
            for (int i = k + 1; i < 8; ++i) {
#pragma unroll
                for (int j = i; j < 8; ++j) {
                    float br = UR[ui(k, j)], bi2 = UI[ui(k, j)];
                    UR[ui(i, j)] -= wr[i] * br - wi[i] * bi2;
                    UI[ui(i, j)] -= wr[i] * bi2 + wi[i] * br;
                }
            }
        }
    }
    float logdet = 0.5f * (__logf(logm) + (float)loge * 0.69314718055994531f);

    const float LOG_DISC_EPS = -27.63102111592855f;   // ln 1e-12
    const float LOG_DELTA2  = -27.63102111592855f;    // 2 ln 1e-6
    const float LOG1P_LEAD  = 1e-12f;                 // log(1 + 1e-12)
    float disc_logabs = logaddexp_f(logdet, LOG_DISC_EPS) - LOG1P_LEAD;
    float log_softabs = 0.5f * logaddexp_f(2.f * disc_logabs, LOG_DELTA2);
    float log_softabs_eps = logaddexp_f(log_softabs, LOG_DISC_EPS);
    float w = __expf(-log_softabs_eps * 0.125f);      // /N_DEG = /8

    float v1 = speed * w, v2 = sp2, v3 = ac2;
#pragma unroll
    for (int off = 32; off; off >>= 1) {
        v1 += __shfl_down(v1, off);
        v2 += __shfl_down(v2, off);
        v3 += __shfl_down(v3, off);
    }
    const int wid = tid >> 6, lane = tid & 63;
    if (lane == 0) { red[wid][0] = v1; red[wid][1] = v2; red[wid][2] = v3; }
    __syncthreads();
    if (tid == 0) {
        float s1 = 0.f, s2 = 0.f, s3 = 0.f;
        for (int w2 = 0; w2 < 4; ++w2) { s1 += red[w2][0]; s2 += red[w2][1]; s3 += red[w2][2]; }
        partial[blockIdx.x * 3 + 0] = s1;
        partial[blockIdx.x * 3 + 1] = s2;
        partial[blockIdx.x * 3 + 2] = s3;
        __threadfence();                              // release partials (device scope)
        int done = atomicAdd(counter, 1);
        lastflag = (done == NBLK - 1) ? 1 : 0;
    }
    __syncthreads();

    // Last arriving block reduces all partials (fixed read order -> deterministic).
    if (lastflag) {
        __threadfence();                              // acquire
        const int b1 = tid, b2 = tid + BLK;
        float u1 = partial[b1 * 3 + 0] + partial[b2 * 3 + 0];
        float u2 = partial[b1 * 3 + 1] + partial[b2 * 3 + 1];
        float u3 = partial[b1 * 3 + 2] + partial[b2 * 3 + 2];
#pragma unroll
        for (int off = 32; off; off >>= 1) {
            u1 += __shfl_down(u1, off);
            u2 += __shfl_down(u2, off);
            u3 += __shfl_down(u3, off);
        }
        if (lane == 0) { red[wid][0] = u1; red[wid][1] = u2; red[wid][2] = u3; }
        __syncthreads();
        if (tid == 0) {
            float s1 = 0.f, s2 = 0.f, s3 = 0.f;
            for (int w2 = 0; w2 < 4; ++w2) { s1 += red[w2][0]; s2 += red[w2][1]; s3 += red[w2][2]; }
            const float Mf = (float)M_SAMPLES;
            out[0] = s1 / Mf + 0.1f * sqrtf(s2 / Mf) + 0.01f * sqrtf(s3 / Mf);
        }
    }
}

extern "C" void kernel_launch(void* const* d_in, const int* in_sizes, int n_in,
                              void* d_out, int out_size, void* d_ws, size_t ws_size,
                              hipStream_t stream) {
    const float* P0   = (const float*)d_in[0];   // (8,2)
    const float* Pd   = (const float*)d_in[1];   // (8,2)
    const float* Pmid = (const float*)d_in[2];   // (6,8,2)
    const float* ts   = (const float*)d_in[3];   // (131072,)
    float* out = (float*)d_out;
    float* partial = (float*)d_ws;                        // NBLK*3 floats (6144 B)
    int* counter = (int*)((char*)d_ws + 8192);            // 4 B arrival counter

    hipMemsetAsync(counter, 0, sizeof(int), stream);      // capture-legal reset
    bez_main_kernel<<<NBLK, BLK, 0, stream>>>(P0, Pd, Pmid, ts, partial, counter, out);
}

// Round 4
// 27.058 us; speedup vs baseline: 2.2446x; 2.2446x over previous
//
#include <hip/hip_runtime.h>
#include <math.h>

#define M_SAMPLES 131072
#define NBLK 512
#define BLK 256

__device__ __forceinline__ float logaddexp_f(float a, float b) {
    float m = fmaxf(a, b);
    float d = fminf(a, b) - m;
    return m + __logf(1.f + __expf(d));
}

#define CMULR(ar, ai, br, bi) ((ar) * (br) - (ai) * (bi))
#define CMULI(ar, ai, br, bi) ((ar) * (bi) + (ai) * (br))

// C(m,k) table (rodata; runtime-indexed loads are memory, not registers)
__device__ const float BINOM[8][8] = {
  {1,0,0,0,0,0,0,0},{1,1,0,0,0,0,0,0},{1,2,1,0,0,0,0,0},{1,3,3,1,0,0,0,0},
  {1,4,6,4,1,0,0,0},{1,5,10,10,5,1,0,0},{1,6,15,20,15,6,1,0},{1,7,21,35,35,21,7,1}};

__global__ __launch_bounds__(BLK) void bez_main_kernel(
    const float* __restrict__ P0, const float* __restrict__ Pd,
    const float* __restrict__ Pmid, const float* __restrict__ ts,
    float* __restrict__ partial, int* __restrict__ counter,
    float* __restrict__ out)
{
    __shared__ float sP[8][8][2];
    __shared__ float sA[8][8][2];   // monomial coeffs: T_j(t) = sum_m A[m][j] t^m
    __shared__ float red[4][3];
    __shared__ int lastflag;

    const int tid = threadIdx.x;
    if (tid < 16) { sP[0][tid >> 1][tid & 1] = P0[tid]; sP[7][tid >> 1][tid & 1] = Pd[tid]; }
    if (tid < 96) { int r = tid / 16, rem = tid % 16; sP[1 + r][rem >> 1][rem & 1] = Pmid[tid]; }
    __syncthreads();
    // Bezier -> monomial: A_m = C(7,m) * sum_{k<=m} (-1)^(m-k) C(m,k) P_k
    if (tid < 128) {
        int m = tid >> 4, rem = tid & 15, j = rem >> 1, c = rem & 1;
        float acc = 0.f;
        float sgn = (m & 1) ? -1.f : 1.f;          // (-1)^m at k=0
        for (int k = 0; k <= m; ++k) {
            acc += sgn * BINOM[m][k] * sP[k][j][c];
            sgn = -sgn;
        }
        sA[m][j][c] = BINOM[7][m] * acc;
    }
    __syncthreads();

    const int gid = blockIdx.x * BLK + tid;
    const float t = ts[gid];

    // Triple Horner: p = T_j, q = T_j', r2 = T_j''/2 — one coefficient set.
    float Tr[8], Ti[8];
    float sp2 = 0.f, ac2 = 0.f;
#pragma unroll
    for (int j = 0; j < 8; ++j) {
        float pr = sA[7][j][0], pi = sA[7][j][1];
        float qr = 0.f, qi = 0.f;
        float rr = 0.f, ri = 0.f;
#pragma unroll
        for (int m = 6; m >= 0; --m) {
            rr = rr * t + qr; ri = ri * t + qi;
            qr = qr * t + pr; qi = qi * t + pi;
            pr = pr * t + sA[m][j][0]; pi = pi * t + sA[m][j][1];
        }
        Tr[j] = pr; Ti[j] = pi;
        sp2 += qr * qr + qi * qi;
        ac2 += rr * rr + ri * ri;
    }
    ac2 *= 4.f;                                    // |T''|^2 = |2*r2|^2
    const float speed = sqrtf(sp2);

    // Ascending coefficients: f_j = T_{7-j} (j=0..7), f_8 = 1 (monic).
    float fr[9], fi[9];
#pragma unroll
    for (int j = 0; j < 8; ++j) { fr[j] = Tr[7 - j]; fi[j] = Ti[7 - j]; }
    fr[8] = 1.f; fi[8] = 0.f;
    // g = f' ascending: g_j = (j+1) f_{j+1}, g_8 = 0
    float gr[9], gi[9];
#pragma unroll
    for (int j = 0; j < 8; ++j) { gr[j] = (float)(j + 1) * fr[j + 1]; gi[j] = (float)(j + 1) * fi[j + 1]; }
    gr[8] = 0.f; gi[8] = 0.f;

    // Antisymmetric pair terms c_{ab} = f_a g_b - f_b g_a, only a<b stored.
    float cR[8][8], cI[8][8];
#pragma unroll
    for (int a = 0; a < 8; ++a) {
#pragma unroll
        for (int b = a + 1; b < 8; ++b) {
            cR[a][b] = (fr[a] * gr[b] - fi[a] * gi[b]) - (fr[b] * gr[a] - fi[b] * gi[a]);
            cI[a][b] = (fr[a] * gi[b] + fi[a] * gr[b]) - (fr[b] * gi[a] + fi[b] * gr[a]);
        }
    }

    // Bezout matrix B (8x8 complex symmetric): |det B| = |Res(f,f')| (f monic).
    // B[7][j] = g_j ; B[i-1][j] = c_{ij} + B[i][j-1]   (full matrix, static idx)
    float Br[8][8], Bi[8][8];
#pragma unroll
    for (int j = 0; j < 8; ++j) { Br[7][j] = gr[j]; Bi[7][j] = gi[j]; }
#pragma unroll
    for (int i = 7; i >= 1; --i) {
#pragma unroll
        for (int j = 0; j < 8; ++j) {
            float cr, ci;
            if (i < j)      { cr = cR[i][j];  ci = cI[i][j]; }
            else if (i > j) { cr = -cR[j][i]; ci = -cI[j][i]; }
            else            { cr = 0.f;       ci = 0.f; }
            if (j >= 1) { cr += Br[i][j - 1]; ci += Bi[i][j - 1]; }
            Br[i - 1][j] = cr; Bi[i - 1][j] = ci;
        }
    }

    // Pivot-free complex-symmetric LDL^T on the upper triangle.
    // log|det| via mantissa-product + exponent-sum (no per-pivot __logf).
    float logm = 1.f; int loge = 0;
#pragma unroll
    for (int k = 0; k < 8; ++k) {
        float dr = Br[k][k], di = Bi[k][k];
        float pm2 = dr * dr + di * di;
        unsigned ub = __float_as_uint(pm2);
        loge += (int)(ub >> 23) - 126;
        logm *= __uint_as_float((ub & 0x007fffffu) | 0x3f000000u);  // [0.5,1)
        if (k < 7) {
            float is = __builtin_amdgcn_rcpf(pm2);
            is = (pm2 > 1e-30f) ? is : 0.f;
            float ivr = dr * is, ivi = -di * is;          // 1/d
            float wr[8], wi[8];
#pragma unroll
            for (int i = k + 1; i < 8; ++i) {
                float ar = Br[k][i], ai = Bi[k][i];       // A[i][k] by symmetry
                wr[i] = ar * ivr - ai * ivi;
                wi[i] = ar * ivi + ai * ivr;
            }
#pragma unroll
            for (int i = k + 1; i < 8; ++i) {
#pragma unroll
                for (int j = i; j < 8; ++j) {
                    float br = Br[k][j], bi2 = Bi[k][j];
                    Br[i][j] -= wr[i] * br - wi[i] * bi2;
                    Bi[i][j] -= wr[i] * bi2 + wi[i] * br;
                }
            }
        }
    }
    float logdet = 0.5f * (__logf(logm) + (float)loge * 0.69314718055994531f);

    const float LOG_DISC_EPS = -27.63102111592855f;   // ln 1e-12
    const float LOG_DELTA2  = -27.63102111592855f;    // 2 ln 1e-6
    const float LOG1P_LEAD  = 1e-12f;                 // log(1 + 1e-12)
    float disc_logabs = logaddexp_f(logdet, LOG_DISC_EPS) - LOG1P_LEAD;
    float log_softabs = 0.5f * logaddexp_f(2.f * disc_logabs, LOG_DELTA2);
    float log_softabs_eps = logaddexp_f(log_softabs, LOG_DISC_EPS);
    float w = __expf(-log_softabs_eps * 0.125f);      // /N_DEG = /8

    float v1 = speed * w, v2 = sp2, v3 = ac2;
#pragma unroll
    for (int off = 32; off; off >>= 1) {
        v1 += __shfl_down(v1, off);
        v2 += __shfl_down(v2, off);
        v3 += __shfl_down(v3, off);
    }
    const int wid = tid >> 6, lane = tid & 63;
    if (lane == 0) { red[wid][0] = v1; red[wid][1] = v2; red[wid][2] = v3; }
    __syncthreads();
    if (tid == 0) {
        float s1 = 0.f, s2 = 0.f, s3 = 0.f;
        for (int w2 = 0; w2 < 4; ++w2) { s1 += red[w2][0]; s2 += red[w2][1]; s3 += red[w2][2]; }
        partial[blockIdx.x * 3 + 0] = s1;
        partial[blockIdx.x * 3 + 1] = s2;
        partial[blockIdx.x * 3 + 2] = s3;
        __threadfence();                              // release partials
        int done = atomicAdd(counter, 1);
        lastflag = (done == NBLK - 1) ? 1 : 0;
    }
    __syncthreads();

    // Last arriving block reduces all partials (fixed order -> deterministic).
    if (lastflag) {
        __threadfence();                              // acquire
        const int b1 = tid, b2 = tid + BLK;
        float u1 = partial[b1 * 3 + 0] + partial[b2 * 3 + 0];
        float u2 = partial[b1 * 3 + 1] + partial[b2 * 3 + 1];
        float u3 = partial[b1 * 3 + 2] + partial[b2 * 3 + 2];
#pragma unroll
        for (int off = 32; off; off >>= 1) {
            u1 += __shfl_down(u1, off);
            u2 += __shfl_down(u2, off);
            u3 += __shfl_down(u3, off);
        }
        if (lane == 0) { red[wid][0] = u1; red[wid][1] = u2; red[wid][2] = u3; }
        __syncthreads();
        if (tid == 0) {
            float s1 = 0.f, s2 = 0.f, s3 = 0.f;
            for (int w2 = 0; w2 < 4; ++w2) { s1 += red[w2][0]; s2 += red[w2][1]; s3 += red[w2][2]; }
            const float Mf = (float)M_SAMPLES;
            out[0] = s1 / Mf + 0.1f * sqrtf(s2 / Mf) + 0.01f * sqrtf(s3 / Mf);
        }
    }
}

extern "C" void kernel_launch(void* const* d_in, const int* in_sizes, int n_in,
                              void* d_out, int out_size, void* d_ws, size_t ws_size,
                              hipStream_t stream) {
    const float* P0   = (const float*)d_in[0];   // (8,2)
    const float* Pd   = (const float*)d_in[1];   // (8,2)
    const float* Pmid = (const float*)d_in[2];   // (6,8,2)
    const float* ts   = (const float*)d_in[3];   // (131072,)
    float* out = (float*)d_out;
    float* partial = (float*)d_ws;                        // NBLK*3 floats (6144 B)
    int* counter = (int*)((char*)d_ws + 8192);            // 4 B arrival counter

    hipMemsetAsync(counter, 0, sizeof(int), stream);      // capture-legal reset
    bez_main_kernel<<<NBLK, BLK, 0, stream>>>(P0, Pd, Pmid, ts, partial, counter, out);
}

// Round 5
// 14.997 us; speedup vs baseline: 4.0498x; 1.8042x over previous
//
#include <hip/hip_runtime.h>
#include <math.h>

#define M_SAMPLES 131072
#define NBLK 512
#define BLK 256

__device__ __forceinline__ float logaddexp_f(float a, float b) {
    float m = fmaxf(a, b);
    float d = fminf(a, b) - m;
    return m + __logf(1.f + __expf(d));
}

// C(m,k) table (rodata; runtime-indexed loads are memory, not registers)
__device__ const float BINOM[8][8] = {
  {1,0,0,0,0,0,0,0},{1,1,0,0,0,0,0,0},{1,2,1,0,0,0,0,0},{1,3,3,1,0,0,0,0},
  {1,4,6,4,1,0,0,0},{1,5,10,10,5,1,0,0},{1,6,15,20,15,6,1,0},{1,7,21,35,35,21,7,1}};

__global__ __launch_bounds__(BLK) void bez_main_kernel(
    const float* __restrict__ P0, const float* __restrict__ Pd,
    const float* __restrict__ Pmid, const float* __restrict__ ts,
    float* __restrict__ partial)
{
    __shared__ float sP[8][8][2];
    __shared__ float sA[8][8][2];   // monomial coeffs: T_j(t) = sum_m A[m][j] t^m
    __shared__ float red[4][3];

    const int tid = threadIdx.x;
    if (tid < 16) { sP[0][tid >> 1][tid & 1] = P0[tid]; sP[7][tid >> 1][tid & 1] = Pd[tid]; }
    if (tid < 96) { int r = tid / 16, rem = tid % 16; sP[1 + r][rem >> 1][rem & 1] = Pmid[tid]; }
    __syncthreads();
    // Bezier -> monomial: A_m = C(7,m) * sum_{k<=m} (-1)^(m-k) C(m,k) P_k
    if (tid < 128) {
        int m = tid >> 4, rem = tid & 15, j = rem >> 1, c = rem & 1;
        float acc = 0.f;
        float sgn = (m & 1) ? -1.f : 1.f;          // (-1)^m at k=0
        for (int k = 0; k <= m; ++k) {
            acc += sgn * BINOM[m][k] * sP[k][j][c];
            sgn = -sgn;
        }
        sA[m][j][c] = BINOM[7][m] * acc;
    }
    __syncthreads();

    const int gid = blockIdx.x * BLK + tid;
    const float t = ts[gid];

    // Triple Horner: p = T_j, q = T_j', r2 = T_j''/2 — one coefficient set.
    float Tr[8], Ti[8];
    float sp2 = 0.f, ac2 = 0.f;
#pragma unroll
    for (int j = 0; j < 8; ++j) {
        float pr = sA[7][j][0], pi = sA[7][j][1];
        float qr = 0.f, qi = 0.f;
        float rr = 0.f, ri = 0.f;
#pragma unroll
        for (int m = 6; m >= 0; --m) {
            rr = rr * t + qr; ri = ri * t + qi;
            qr = qr * t + pr; qi = qi * t + pi;
            pr = pr * t + sA[m][j][0]; pi = pi * t + sA[m][j][1];
        }
        Tr[j] = pr; Ti[j] = pi;
        sp2 += qr * qr + qi * qi;
        ac2 += rr * rr + ri * ri;
    }
    ac2 *= 4.f;                                    // |T''|^2 = |2*r2|^2
    const float speed = sqrtf(sp2);

    // Ascending coefficients: f_j = T_{7-j} (j=0..7), f_8 = 1 (monic).
    float fr[9], fi[9];
#pragma unroll
    for (int j = 0; j < 8; ++j) { fr[j] = Tr[7 - j]; fi[j] = Ti[7 - j]; }
    fr[8] = 1.f; fi[8] = 0.f;
    // u_k = k * f_k  (so g_j = f'_j = u_{j+1})
    float ur[9], uii[9];
#pragma unroll
    for (int k = 1; k < 9; ++k) { ur[k] = (float)k * fr[k]; uii[k] = (float)k * fi[k]; }

    // Antisymmetric pair terms c_{a,b} = f_a g_b - f_b g_a = f_a u_{b+1} - f_b u_{a+1}
    float cR[8][8], cI[8][8];
#pragma unroll
    for (int a = 0; a < 8; ++a) {
#pragma unroll
        for (int b = a + 1; b < 8; ++b) {
            cR[a][b] = (fr[a] * ur[b + 1] - fi[a] * uii[b + 1]) - (fr[b] * ur[a + 1] - fi[b] * uii[a + 1]);
            cI[a][b] = (fr[a] * uii[b + 1] + fi[a] * ur[b + 1]) - (fr[b] * uii[a + 1] + fi[b] * ur[a + 1]);
        }
    }

    // Bezout matrix B (8x8 complex symmetric): |det B| = |Res(f,f')| (f monic).
    // B[7][j] = g_j = u_{j+1} ; B[i-1][j] = c_{ij} + B[i][j-1]  (static idx)
    float Br[8][8], Bi[8][8];
#pragma unroll
    for (int j = 0; j < 8; ++j) { Br[7][j] = ur[j + 1]; Bi[7][j] = uii[j + 1]; }
#pragma unroll
    for (int i = 7; i >= 1; --i) {
#pragma unroll
        for (int j = 0; j < 8; ++j) {
            float cr, ci;
            if (i < j)      { cr = cR[i][j];  ci = cI[i][j]; }
            else if (i > j) { cr = -cR[j][i]; ci = -cI[j][i]; }
            else            { cr = 0.f;       ci = 0.f; }
            if (j >= 1) { cr += Br[i][j - 1]; ci += Bi[i][j - 1]; }
            Br[i - 1][j] = cr; Bi[i - 1][j] = ci;
        }
    }

    // Pivot-free complex-symmetric LDL^T on the upper triangle.
    // log|det| via mantissa-product + exponent-sum (no per-pivot __logf).
    float logm = 1.f; int loge = 0;
#pragma unroll
    for (int k = 0; k < 8; ++k) {
        float dr = Br[k][k], di = Bi[k][k];
        float pm2 = dr * dr + di * di;
        unsigned ub = __float_as_uint(pm2);
        loge += (int)(ub >> 23) - 126;
        logm *= __uint_as_float((ub & 0x007fffffu) | 0x3f000000u);  // [0.5,1)
        if (k < 7) {
            float is = __builtin_amdgcn_rcpf(pm2);
            is = (pm2 > 1e-30f) ? is : 0.f;
            float ivr = dr * is, ivi = -di * is;          // 1/d
            float wr[8], wi[8];
#pragma unroll
            for (int i = k + 1; i < 8; ++i) {
                float ar = Br[k][i], ai = Bi[k][i];       // A[i][k] by symmetry
                wr[i] = ar * ivr - ai * ivi;
                wi[i] = ar * ivi + ai * ivr;
            }
#pragma unroll
            for (int i = k + 1; i < 8; ++i) {
#pragma unroll
                for (int j = i; j < 8; ++j) {
                    float br = Br[k][j], bi2 = Bi[k][j];
                    Br[i][j] -= wr[i] * br - wi[i] * bi2;
                    Bi[i][j] -= wr[i] * bi2 + wi[i] * br;
                }
            }
        }
    }
    float logdet = 0.5f * (__logf(logm) + (float)loge * 0.69314718055994531f);

    const float LOG_DISC_EPS = -27.63102111592855f;   // ln 1e-12
    const float LOG_DELTA2  = -27.63102111592855f;    // 2 ln 1e-6
    const float LOG1P_LEAD  = 1e-12f;                 // log(1 + 1e-12)
    float disc_logabs = logaddexp_f(logdet, LOG_DISC_EPS) - LOG1P_LEAD;
    float log_softabs = 0.5f * logaddexp_f(2.f * disc_logabs, LOG_DELTA2);
    float log_softabs_eps = logaddexp_f(log_softabs, LOG_DISC_EPS);
    float w = __expf(-log_softabs_eps * 0.125f);      // /N_DEG = /8

    float v1 = speed * w, v2 = sp2, v3 = ac2;
#pragma unroll
    for (int off = 32; off; off >>= 1) {
        v1 += __shfl_down(v1, off);
        v2 += __shfl_down(v2, off);
        v3 += __shfl_down(v3, off);
    }
    const int wid = tid >> 6, lane = tid & 63;
    if (lane == 0) { red[wid][0] = v1; red[wid][1] = v2; red[wid][2] = v3; }
    __syncthreads();
    if (tid == 0) {
        float s1 = 0.f, s2 = 0.f, s3 = 0.f;
        for (int w2 = 0; w2 < 4; ++w2) { s1 += red[w2][0]; s2 += red[w2][1]; s3 += red[w2][2]; }
        partial[blockIdx.x * 3 + 0] = s1;
        partial[blockIdx.x * 3 + 1] = s2;
        partial[blockIdx.x * 3 + 2] = s3;
    }
}

__global__ __launch_bounds__(NBLK) void bez_finalize_kernel(
    const float* __restrict__ partial, float* __restrict__ out)
{
    const int tid = threadIdx.x;
    float v1 = partial[tid * 3 + 0];
    float v2 = partial[tid * 3 + 1];
    float v3 = partial[tid * 3 + 2];
#pragma unroll
    for (int off = 32; off; off >>= 1) {
        v1 += __shfl_down(v1, off);
        v2 += __shfl_down(v2, off);
        v3 += __shfl_down(v3, off);
    }
    __shared__ float red[8][3];
    const int wid = tid >> 6, lane = tid & 63;
    if (lane == 0) { red[wid][0] = v1; red[wid][1] = v2; red[wid][2] = v3; }
    __syncthreads();
    if (tid == 0) {
        float s1 = 0.f, s2 = 0.f, s3 = 0.f;
        for (int w2 = 0; w2 < 8; ++w2) { s1 += red[w2][0]; s2 += red[w2][1]; s3 += red[w2][2]; }
        const float Mf = (float)M_SAMPLES;
        out[0] = s1 / Mf + 0.1f * sqrtf(s2 / Mf) + 0.01f * sqrtf(s3 / Mf);
    }
}

extern "C" void kernel_launch(void* const* d_in, const int* in_sizes, int n_in,
                              void* d_out, int out_size, void* d_ws, size_t ws_size,
                              hipStream_t stream) {
    const float* P0   = (const float*)d_in[0];   // (8,2)
    const float* Pd   = (const float*)d_in[1];   // (8,2)
    const float* Pmid = (const float*)d_in[2];   // (6,8,2)
    const float* ts   = (const float*)d_in[3];   // (131072,)
    float* out = (float*)d_out;
    float* partial = (float*)d_ws;               // NBLK*3 floats

    bez_main_kernel<<<NBLK, BLK, 0, stream>>>(P0, Pd, Pmid, ts, partial);
    bez_finalize_kernel<<<1, NBLK, 0, stream>>>(partial, out);
}